// Round 1
// baseline (401.185 us; speedup 1.0000x reference)
//
#include <hip/hip_runtime.h>

// ---------- common types ----------
typedef float  f32x4  __attribute__((ext_vector_type(4)));
typedef short  bf16x8 __attribute__((ext_vector_type(8)));

#define MFMA16(a, b, c) __builtin_amdgcn_mfma_f32_16x16x32_bf16((a), (b), (c), 0, 0, 0)

__device__ __forceinline__ short f2bf(float f) {
    union { float f; unsigned u; } a; a.f = f;
    unsigned r = a.u + 0x7fffu + ((a.u >> 16) & 1u);  // RNE
    return (short)(r >> 16);
}

// sizes
#define Bb   8
#define Nn   1024
#define DIM  768
#define HH   12
#define HD   64
#define INNER 768
#define SCALE 0.125f

// ---------- prep kernels ----------
__global__ void cast_to_bf16(const float* __restrict__ in, short* __restrict__ out, int n4) {
    int i = blockIdx.x * 256 + threadIdx.x;
    if (i >= n4) return;
    float4 f = reinterpret_cast<const float4*>(in)[i];
    unsigned lo = (unsigned)(unsigned short)f2bf(f.x) | ((unsigned)(unsigned short)f2bf(f.y) << 16);
    unsigned hi = (unsigned)(unsigned short)f2bf(f.z) | ((unsigned)(unsigned short)f2bf(f.w) << 16);
    reinterpret_cast<uint2*>(out)[i] = make_uint2(lo, hi);
}

// wt[c][k] = w[k][c]; w is [rows=K][cols], wt is [cols][K]
__global__ void transpose_cast(const float* __restrict__ w, short* __restrict__ wt,
                               int rows, int cols) {
    int idx = blockIdx.x * 256 + threadIdx.x;
    if (idx >= rows * cols) return;
    int c = idx / rows;
    int k = idx - c * rows;
    wt[idx] = f2bf(w[k * cols + c]);
}

// ---------- GEMM: C[M,N] = A[M,K] @ Bt[N,K]^T ----------
// 128x128 block tile, 4 waves in 2x2, each wave 64x64 (4x4 of 16x16 mfma tiles), BK=32
// MODE 0: QKV epilogue -> scatter to qb [b,h,n,d], kb [b,h,n,d], vtb [b,h,d,n] (bf16)
// MODE 1: out-proj epilogue -> fp32 out + bias
template <int MODE>
__global__ __launch_bounds__(256, 2)
void gemm128(const short* __restrict__ A, const short* __restrict__ Bt, int K,
             short* __restrict__ qb, short* __restrict__ kb, short* __restrict__ vtb,
             float* __restrict__ outp, const float* __restrict__ bias) {
    __shared__ __align__(16) short As[128 * 40];
    __shared__ __align__(16) short Bs[128 * 40];

    const int tid  = threadIdx.x;
    const int lane = tid & 63, wv = tid >> 6;
    const int wrow = wv >> 1, wcol = wv & 1;
    const int quad = lane >> 4, l16 = lane & 15;
    const int m0 = blockIdx.y * 128, n0 = blockIdx.x * 128;

    // staging map: each thread loads 32B of A and 32B of B (row = tid>>1, 16 bf16)
    const int srow = tid >> 1;
    const int soff = (tid & 1) * 16;

    f32x4 acc[4][4];
#pragma unroll
    for (int i = 0; i < 4; i++)
#pragma unroll
        for (int j = 0; j < 4; j++) acc[i][j] = (f32x4){0.f, 0.f, 0.f, 0.f};

    for (int kc = 0; kc < K; kc += 32) {
        const uint4 a0 = *reinterpret_cast<const uint4*>(A + (size_t)(m0 + srow) * K + kc + soff);
        const uint4 a1 = *reinterpret_cast<const uint4*>(A + (size_t)(m0 + srow) * K + kc + soff + 8);
        const uint4 b0 = *reinterpret_cast<const uint4*>(Bt + (size_t)(n0 + srow) * K + kc + soff);
        const uint4 b1 = *reinterpret_cast<const uint4*>(Bt + (size_t)(n0 + srow) * K + kc + soff + 8);
        __syncthreads();  // previous-iter LDS reads done before overwrite
        *reinterpret_cast<uint4*>(&As[srow * 40 + soff])     = a0;
        *reinterpret_cast<uint4*>(&As[srow * 40 + soff + 8]) = a1;
        *reinterpret_cast<uint4*>(&Bs[srow * 40 + soff])     = b0;
        *reinterpret_cast<uint4*>(&Bs[srow * 40 + soff + 8]) = b1;
        __syncthreads();

        bf16x8 af[4], bfr[4];
#pragma unroll
        for (int t = 0; t < 4; t++)
            af[t] = *reinterpret_cast<bf16x8*>(&As[(wrow * 64 + t * 16 + l16) * 40 + quad * 8]);
#pragma unroll
        for (int t = 0; t < 4; t++)
            bfr[t] = *reinterpret_cast<bf16x8*>(&Bs[(wcol * 64 + t * 16 + l16) * 40 + quad * 8]);
#pragma unroll
        for (int rt = 0; rt < 4; rt++)
#pragma unroll
            for (int ct = 0; ct < 4; ct++)
                acc[rt][ct] = MFMA16(af[rt], bfr[ct], acc[rt][ct]);
    }

    // epilogue: C/D layout col=lane&15, row=quad*4+reg (verified m89/m91)
#pragma unroll
    for (int rt = 0; rt < 4; rt++) {
#pragma unroll
        for (int ct = 0; ct < 4; ct++) {
            const int c = n0 + wcol * 64 + ct * 16 + l16;
#pragma unroll
            for (int reg = 0; reg < 4; reg++) {
                const int r = m0 + wrow * 64 + rt * 16 + quad * 4 + reg;
                const float v = acc[rt][ct][reg];
                if (MODE == 0) {
                    const int b = r >> 10, n = r & 1023;
                    const int which = (c >= 1536) ? 2 : (c >= 768 ? 1 : 0);
                    const int cc = c - which * 768;
                    const int h = cc >> 6, d = cc & 63;
                    const int bh = b * HH + h;
                    const short bv = f2bf(v);
                    if (which == 0)      qb[(bh << 16) + (n << 6) + d] = bv;
                    else if (which == 1) kb[(bh << 16) + (n << 6) + d] = bv;
                    else                 vtb[(bh << 16) + (d << 10) + n] = bv;
                } else {
                    outp[(size_t)r * 768 + c] = v + bias[c];
                }
            }
        }
    }
}

// ---------- fused attention ----------
// grid: B * (N/16) = 512 blocks, 256 threads (4 waves)
// block handles (b, 16 query rows). m-loop in tiles of 32.
// wave w computes S for heads 3w..3w+2; softmax over h via LDS; wave w does PV for d-chunk [16w,16w+16)
__global__ __launch_bounds__(256, 2)
void attn_fused(const short* __restrict__ qb, const short* __restrict__ kb,
                const short* __restrict__ vtb, short* __restrict__ attn_out) {
    __shared__ __align__(16) float sS[512 * 13];       // [pos=n*32+m][h], stride 13 to break banks
    __shared__ __align__(16) short pP[12 * 16 * 40];   // [h][n][m] bf16, row stride 40

    const int tid = threadIdx.x, lane = tid & 63, wv = tid >> 6;
    const int quad = lane >> 4, l16 = lane & 15;
    const int b = blockIdx.x >> 6;
    const int n0 = (blockIdx.x & 63) << 4;
    const int hb = wv * 3;

    // Q fragments for this wave's 3 heads (A-layout: row=l16, k=quad*8+j), K=64 -> 2 frags
    bf16x8 aq[3][2];
#pragma unroll
    for (int hh = 0; hh < 3; hh++) {
        const short* qp = qb + ((b * HH + hb + hh) << 16) + ((n0 + l16) << 6) + quad * 8;
        aq[hh][0] = *reinterpret_cast<const bf16x8*>(qp);
        aq[hh][1] = *reinterpret_cast<const bf16x8*>(qp + 32);
    }

    f32x4 O[12];
#pragma unroll
    for (int h = 0; h < 12; h++) O[h] = (f32x4){0.f, 0.f, 0.f, 0.f};
    const f32x4 z = (f32x4){0.f, 0.f, 0.f, 0.f};

    for (int m0 = 0; m0 < Nn; m0 += 32) {
        // Phase A: S for 3 heads, two 16-m halves each
        f32x4 s[3][2];
#pragma unroll
        for (int hh = 0; hh < 3; hh++) {
#pragma unroll
            for (int mh = 0; mh < 2; mh++) {
                const short* kp = kb + ((b * HH + hb + hh) << 16) + ((m0 + mh * 16 + l16) << 6) + quad * 8;
                bf16x8 k0 = *reinterpret_cast<const bf16x8*>(kp);
                bf16x8 k1 = *reinterpret_cast<const bf16x8*>(kp + 32);
                f32x4 cc = MFMA16(aq[hh][0], k0, z);
                cc = MFMA16(aq[hh][1], k1, cc);
                s[hh][mh] = cc;
            }
        }
        // write S to LDS [pos][h]
#pragma unroll
        for (int hh = 0; hh < 3; hh++)
#pragma unroll
            for (int mh = 0; mh < 2; mh++)
#pragma unroll
                for (int reg = 0; reg < 4; reg++) {
                    const int n = quad * 4 + reg, m = mh * 16 + l16;
                    sS[(n * 32 + m) * 13 + hb + hh] = s[hh][mh][reg];
                }
        __syncthreads();

        // Phase B: softmax over h at each of 512 (n,m) positions; 2 per thread
#pragma unroll
        for (int pi = 0; pi < 2; pi++) {
            const int pos = tid + pi * 256;
            const float* sp = &sS[pos * 13];
            float v[12];
            float mx = -1e30f;
#pragma unroll
            for (int h = 0; h < 12; h++) { v[h] = sp[h] * SCALE; mx = fmaxf(mx, v[h]); }
            float sum = 0.f;
#pragma unroll
            for (int h = 0; h < 12; h++) { v[h] = __expf(v[h] - mx); sum += v[h]; }
            const float inv = 1.0f / sum;
            const int n = pos >> 5, m = pos & 31;
#pragma unroll
            for (int h = 0; h < 12; h++) pP[(h * 16 + n) * 40 + m] = f2bf(v[h] * inv);
        }
        __syncthreads();

        // Phase C: PV for this wave's d-chunk [16*wv, 16*wv+16)
#pragma unroll
        for (int h = 0; h < 12; h++) {
            bf16x8 pa = *reinterpret_cast<bf16x8*>(&pP[(h * 16 + l16) * 40 + quad * 8]);
            const short* vp = vtb + ((b * HH + h) << 16) + ((wv * 16 + l16) << 10) + m0 + quad * 8;
            bf16x8 vf = *reinterpret_cast<const bf16x8*>(vp);
            O[h] = MFMA16(pa, vf, O[h]);
        }
        // next-iter Phase A writes sS only (safe: B's sS reads ended before barrier2);
        // next-iter Phase B writes pP after barrier1 (safe vs this C's pP reads).
    }

    // epilogue: O C-layout row=quad*4+reg (n), col=l16 (d within chunk)
#pragma unroll
    for (int h = 0; h < 12; h++) {
        const int col = h * 64 + wv * 16 + l16;
#pragma unroll
        for (int reg = 0; reg < 4; reg++) {
            const int n = quad * 4 + reg;
            attn_out[(size_t)((b << 10) + n0 + n) * 768 + col] = f2bf(O[h][reg]);
        }
    }
}

// ---------- launch ----------
extern "C" void kernel_launch(void* const* d_in, const int* in_sizes, int n_in,
                              void* d_out, int out_size, void* d_ws, size_t ws_size,
                              hipStream_t stream) {
    const float* x     = (const float*)d_in[0];
    const float* w_qkv = (const float*)d_in[1];
    const float* w_out = (const float*)d_in[2];
    const float* b_out = (const float*)d_in[3];
    float* out = (float*)d_out;

    // workspace carving (all bf16 as short)
    short* xb   = (short*)d_ws;                 // [8192][768]
    short* wT1  = xb  + 8192 * 768;             // [2304][768]
    short* wT2  = wT1 + 2304 * 768;             // [768][768]
    short* qb   = wT2 + 768 * 768;              // [b][h][n][d] = 96*1024*64
    short* kb   = qb  + 96 * 65536;
    short* vtb  = kb  + 96 * 65536;             // [b][h][d][n]
    short* attn = vtb + 96 * 65536;             // [8192][768]

    cast_to_bf16<<<6144, 256, 0, stream>>>(x, xb, (8192 * 768) / 4);
    transpose_cast<<<(2304 * 768) / 256, 256, 0, stream>>>(w_qkv, wT1, 768, 2304);
    transpose_cast<<<(768 * 768) / 256, 256, 0, stream>>>(w_out, wT2, 768, 768);

    gemm128<0><<<dim3(2304 / 128, 8192 / 128), 256, 0, stream>>>(
        xb, wT1, 768, qb, kb, vtb, nullptr, nullptr);

    attn_fused<<<Bb * (Nn / 16), 256, 0, stream>>>(qb, kb, vtb, attn);

    gemm128<1><<<dim3(768 / 128, 8192 / 128), 256, 0, stream>>>(
        attn, wT2, 768, nullptr, nullptr, nullptr, out, b_out);
}